// Round 8
// baseline (305.995 us; speedup 1.0000x reference)
//
#include <hip/hip_runtime.h>
#include <math.h>

#define NP 3136
#define NC 256
#define NB 16
#define HH 56
#define OW 224

typedef __attribute__((ext_vector_type(8))) short bh8;
typedef __attribute__((ext_vector_type(4))) float fx4;

// split fp32x8 -> hi/lo bf16x8 (truncation; x = hi + lo + O(2^-16 x), both
// subtractions exact in fp32)
__device__ __forceinline__ void cvt8(const float4 u, const float4 v,
                                     bh8& hi, bh8& lo) {
  union U { unsigned int w[4]; bh8 vec; };
  U H, L;
  const unsigned int a0 = __float_as_uint(u.x), a1 = __float_as_uint(u.y),
                     a2 = __float_as_uint(u.z), a3 = __float_as_uint(u.w),
                     a4 = __float_as_uint(v.x), a5 = __float_as_uint(v.y),
                     a6 = __float_as_uint(v.z), a7 = __float_as_uint(v.w);
  H.w[0] = (a0 >> 16) | (a1 & 0xffff0000u);
  H.w[1] = (a2 >> 16) | (a3 & 0xffff0000u);
  H.w[2] = (a4 >> 16) | (a5 & 0xffff0000u);
  H.w[3] = (a6 >> 16) | (a7 & 0xffff0000u);
  const float r0 = u.x - __uint_as_float(a0 & 0xffff0000u);
  const float r1 = u.y - __uint_as_float(a1 & 0xffff0000u);
  const float r2 = u.z - __uint_as_float(a2 & 0xffff0000u);
  const float r3 = u.w - __uint_as_float(a3 & 0xffff0000u);
  const float r4 = v.x - __uint_as_float(a4 & 0xffff0000u);
  const float r5 = v.y - __uint_as_float(a5 & 0xffff0000u);
  const float r6 = v.z - __uint_as_float(a6 & 0xffff0000u);
  const float r7 = v.w - __uint_as_float(a7 & 0xffff0000u);
  L.w[0] = (__float_as_uint(r0) >> 16) | (__float_as_uint(r1) & 0xffff0000u);
  L.w[1] = (__float_as_uint(r2) >> 16) | (__float_as_uint(r3) & 0xffff0000u);
  L.w[2] = (__float_as_uint(r4) >> 16) | (__float_as_uint(r5) & 0xffff0000u);
  L.w[3] = (__float_as_uint(r6) >> 16) | (__float_as_uint(r7) & 0xffff0000u);
  hi = H.vec;
  lo = L.vec;
}

// ---------------- Stage 1: Mahalanobis distance via MFMA ----------------
// One block per p, 4 waves. S = M_p (256x256) * Delta_p (256x16) computed with
// mfma_f32_16x16x32_bf16 in split-bf16 (AhiBhi + AhiBlo + AloBhi); then
// d2[b] = sum_c Delta[c][b] * S[c][b] in fp32.
// Wave wv owns rows [wv*64, wv*64+64) as 4 tiles of 16. A-fragments are read
// directly from global (full cache-line utilization), 1 kstep prefetch ahead.
// A-frag: lane holds M[r0+(l&15)][ks*32 + (l>>4)*8 + i], i=0..7.
// B-frag: lane holds Delta[ks*32 + (l>>4)*8 + i][l&15] from [b][k] LDS (+pad).
// C/D: col b = l&15, row = (l>>4)*4 + reg  (m89-verified mapping).
__global__ __launch_bounds__(256, 4) void k_dist(const float* __restrict__ emb,
                                                 const float* __restrict__ means,
                                                 const float* __restrict__ icov,
                                                 float* __restrict__ dist) {
  __shared__ float dc_lds[NC][20];  // Delta[c][b] fp32 (final multiply)
  __shared__ __align__(16) unsigned short Bhi[16 * 264];  // [b][k], stride 264
  __shared__ __align__(16) unsigned short Blo[16 * 264];
  __shared__ float zbuf[4][16];

  const int bid = blockIdx.x;
  const int p = (bid & 7) * (NP >> 3) + (bid >> 3);  // XCD swizzle (3136%8==0)
  const int t = threadIdx.x;
  const int lane = t & 63;
  const int wv = t >> 6;

  const float* gbase = icov + (size_t)p * (NC * NC) +
                       ((size_t)(wv * 64) + (lane & 15)) * NC + ((lane >> 4) * 8);
#define LD(tl, ks, h) \
  (*reinterpret_cast<const float4*>(gbase + (tl)*4096 + (ks)*32 + (h)*4))

  // issue first A-loads immediately (overlap with staging below)
  float4 cA[4][2];
#pragma unroll
  for (int tl = 0; tl < 4; ++tl) {
    cA[tl][0] = LD(tl, 0, 0);
    cA[tl][1] = LD(tl, 0, 1);
  }

  // stage Delta[c][b] = emb[b][c][p] - means[p][c]; thread t owns c = t
  // (strided emb gather is L3-absorbed — R3 verified)
  {
    const int c = t;
    const float mn = means[(size_t)p * NC + c];
    const float* ep = emb + (size_t)c * NP + p;
    float d[16];
#pragma unroll
    for (int b = 0; b < 16; ++b) d[b] = ep[(size_t)b * (NC * NP)] - mn;
#pragma unroll
    for (int q = 0; q < 4; ++q) {
      *reinterpret_cast<float4*>(&dc_lds[c][4 * q]) =
          make_float4(d[4 * q], d[4 * q + 1], d[4 * q + 2], d[4 * q + 3]);
    }
  }
  __syncthreads();

  // build split-bf16 B operand: Bhi/Blo[b][k] (thread t: b = t>>4, 16 k's)
  {
    const int bb = t >> 4;
    const int k0 = (t & 15) * 16;
#pragma unroll
    for (int kk = 0; kk < 16; ++kk) {
      const float x = dc_lds[k0 + kk][bb];
      const unsigned int xb = __float_as_uint(x);
      const float rem = x - __uint_as_float(xb & 0xffff0000u);
      Bhi[bb * 264 + k0 + kk] = (unsigned short)(xb >> 16);
      Blo[bb * 264 + k0 + kk] = (unsigned short)(__float_as_uint(rem) >> 16);
    }
  }
  __syncthreads();

  fx4 acc0 = {0.f, 0.f, 0.f, 0.f}, acc1 = acc0, acc2 = acc0, acc3 = acc0;

#pragma unroll
  for (int ks = 0; ks < 8; ++ks) {
    float4 nA[4][2];
    if (ks < 7) {
#pragma unroll
      for (int tl = 0; tl < 4; ++tl) {
        nA[tl][0] = LD(tl, ks + 1, 0);
        nA[tl][1] = LD(tl, ks + 1, 1);
      }
    }
    const int kb = ks * 32 + (lane >> 4) * 8;
    const bh8 bhi = *reinterpret_cast<const bh8*>(&Bhi[(lane & 15) * 264 + kb]);
    const bh8 blo = *reinterpret_cast<const bh8*>(&Blo[(lane & 15) * 264 + kb]);
    bh8 ahi, alo;
    cvt8(cA[0][0], cA[0][1], ahi, alo);
    acc0 = __builtin_amdgcn_mfma_f32_16x16x32_bf16(ahi, bhi, acc0, 0, 0, 0);
    acc0 = __builtin_amdgcn_mfma_f32_16x16x32_bf16(ahi, blo, acc0, 0, 0, 0);
    acc0 = __builtin_amdgcn_mfma_f32_16x16x32_bf16(alo, bhi, acc0, 0, 0, 0);
    cvt8(cA[1][0], cA[1][1], ahi, alo);
    acc1 = __builtin_amdgcn_mfma_f32_16x16x32_bf16(ahi, bhi, acc1, 0, 0, 0);
    acc1 = __builtin_amdgcn_mfma_f32_16x16x32_bf16(ahi, blo, acc1, 0, 0, 0);
    acc1 = __builtin_amdgcn_mfma_f32_16x16x32_bf16(alo, bhi, acc1, 0, 0, 0);
    cvt8(cA[2][0], cA[2][1], ahi, alo);
    acc2 = __builtin_amdgcn_mfma_f32_16x16x32_bf16(ahi, bhi, acc2, 0, 0, 0);
    acc2 = __builtin_amdgcn_mfma_f32_16x16x32_bf16(ahi, blo, acc2, 0, 0, 0);
    acc2 = __builtin_amdgcn_mfma_f32_16x16x32_bf16(alo, bhi, acc2, 0, 0, 0);
    cvt8(cA[3][0], cA[3][1], ahi, alo);
    acc3 = __builtin_amdgcn_mfma_f32_16x16x32_bf16(ahi, bhi, acc3, 0, 0, 0);
    acc3 = __builtin_amdgcn_mfma_f32_16x16x32_bf16(ahi, blo, acc3, 0, 0, 0);
    acc3 = __builtin_amdgcn_mfma_f32_16x16x32_bf16(alo, bhi, acc3, 0, 0, 0);
    if (ks < 7) {
#pragma unroll
      for (int tl = 0; tl < 4; ++tl) {
        cA[tl][0] = nA[tl][0];
        cA[tl][1] = nA[tl][1];
      }
    }
  }
#undef LD

  // z = sum_c Delta[c][b] * S[c][b] over this wave's 64 rows (b = lane&15)
  const int b = lane & 15;
  const int rj = (lane >> 4) * 4;
  float zz = 0.f;
#pragma unroll
  for (int j = 0; j < 4; ++j) {
    zz = fmaf(dc_lds[wv * 64 + 0 * 16 + rj + j][b], acc0[j], zz);
    zz = fmaf(dc_lds[wv * 64 + 1 * 16 + rj + j][b], acc1[j], zz);
    zz = fmaf(dc_lds[wv * 64 + 2 * 16 + rj + j][b], acc2[j], zz);
    zz = fmaf(dc_lds[wv * 64 + 3 * 16 + rj + j][b], acc3[j], zz);
  }
  zz += __shfl_xor(zz, 16, 64);
  zz += __shfl_xor(zz, 32, 64);
  if (lane < 16) zbuf[wv][lane] = zz;
  __syncthreads();
  if (t < 16) {
    const float d2 = zbuf[0][t] + zbuf[1][t] + zbuf[2][t] + zbuf[3][t];
    dist[(size_t)t * NP + p] = sqrtf(d2);
  }
}

// ---------------- Stage 2a: fused bilinear-resize + row gaussian blur --------
__global__ __launch_bounds__(256) void k_rowblur(const float* __restrict__ dist,
                                                 float* __restrict__ out,
                                                 unsigned int* __restrict__ mm) {
  __shared__ float w[33];
  __shared__ float row[256];
  const int t = threadIdx.x;
  const int by = blockIdx.x;  // b*224 + y
  const int b = by / OW, y = by - b * OW;
  if (by == 0 && t == 0) { mm[0] = 0x7f800000u; mm[1] = 0u; }  // init for colblur
  if (t < 33) {
    const float d = (float)(t - 16);
    w[t] = expf(-d * d * (1.f / 32.f));
  }
  int xi = t - 16;  // [-16, 239] -> reflect into [0, 224)
  xi = (xi < 0) ? (-xi - 1) : xi;
  xi = (xi >= OW) ? (2 * OW - 1 - xi) : xi;
  const float sy = y * 0.25f - 0.375f;
  const float sx = xi * 0.25f - 0.375f;
  const int y0 = (int)floorf(sy), x0 = (int)floorf(sx);
  const float fy = sy - (float)y0, fx = sx - (float)x0;
  const int y0c = y0 < 0 ? 0 : (y0 > HH - 1 ? HH - 1 : y0);
  const int y1c = (y0 + 1) > HH - 1 ? HH - 1 : (y0 + 1 < 0 ? 0 : y0 + 1);
  const int x0c = x0 < 0 ? 0 : (x0 > HH - 1 ? HH - 1 : x0);
  const int x1c = (x0 + 1) > HH - 1 ? HH - 1 : (x0 + 1 < 0 ? 0 : x0 + 1);
  const float* db = dist + (size_t)b * NP;
  const float v00 = db[y0c * HH + x0c], v01 = db[y0c * HH + x1c];
  const float v10 = db[y1c * HH + x0c], v11 = db[y1c * HH + x1c];
  const float v0 = v00 + fx * (v01 - v00);
  const float v1 = v10 + fx * (v11 - v10);
  row[t] = v0 + fy * (v1 - v0);
  __syncthreads();
  if (t < OW) {
    float a = 0.f;
#pragma unroll
    for (int k = 0; k < 33; ++k) a = fmaf(w[k], row[t + k], a);
    out[(size_t)by * OW + t] = a;
  }
}

// ---------------- Stage 2b: column gaussian blur + global min/max ------------
__global__ __launch_bounds__(256) void k_colblur(const float* __restrict__ in,
                                                 float* __restrict__ out,
                                                 unsigned int* __restrict__ mm) {
  __shared__ float w[33];
  __shared__ float red[4][2];
  const int t = threadIdx.x;
  const int by = blockIdx.x;  // b*224 + y
  const int b = by / OW, y = by - b * OW;
  if (t < 33) {
    const float d = (float)(t - 16);
    w[t] = expf(-d * d * (1.f / 32.f));
  }
  __syncthreads();
  float a = 0.f;
  const float* bp = in + (size_t)b * OW * OW;
  if (t < OW) {
#pragma unroll
    for (int k = 0; k < 33; ++k) {
      int yi = y + k - 16;
      yi = (yi < 0) ? (-yi - 1) : yi;
      yi = (yi >= OW) ? (2 * OW - 1 - yi) : yi;
      a = fmaf(w[k], bp[(size_t)yi * OW + t], a);
    }
    out[(size_t)by * OW + t] = a;
  }
  float mnv = (t < OW) ? a : 3.0e38f;
  float mxv = (t < OW) ? a : 0.f;
#pragma unroll
  for (int off = 32; off > 0; off >>= 1) {
    mnv = fminf(mnv, __shfl_xor(mnv, off, 64));
    mxv = fmaxf(mxv, __shfl_xor(mxv, off, 64));
  }
  const int lane = t & 63, wv = t >> 6;
  if (lane == 0) { red[wv][0] = mnv; red[wv][1] = mxv; }
  __syncthreads();
  if (t == 0) {
    const float m0 = fminf(fminf(red[0][0], red[1][0]), fminf(red[2][0], red[3][0]));
    const float m1 = fmaxf(fmaxf(red[0][1], red[1][1]), fmaxf(red[2][1], red[3][1]));
    atomicMin(&mm[0], __float_as_uint(m0));
    atomicMax(&mm[1], __float_as_uint(m1));
  }
}

// ---------------- Stage 2c: normalize (float4) ----------------
__global__ __launch_bounds__(256) void k_norm(const float4* __restrict__ in,
                                              const unsigned int* __restrict__ mm,
                                              float4* __restrict__ out) {
  const int i = blockIdx.x * 256 + threadIdx.x;  // 200704 float4s exactly
  const float mn = __uint_as_float(mm[0]);
  const float mx = __uint_as_float(mm[1]);
  const float inv = 1.f / (mx - mn);
  const float4 v = in[i];
  out[i] = make_float4((v.x - mn) * inv, (v.y - mn) * inv,
                       (v.z - mn) * inv, (v.w - mn) * inv);
}

extern "C" void kernel_launch(void* const* d_in, const int* in_sizes, int n_in,
                              void* d_out, int out_size, void* d_ws, size_t ws_size,
                              hipStream_t stream) {
  const float* emb = (const float*)d_in[0];    // [16,256,3136]
  const float* means = (const float*)d_in[1];  // [3136,256]
  const float* icov = (const float*)d_in[2];   // [3136,256,256]
  float* out = (float*)d_out;                  // [16,224,224]

  char* ws = (char*)d_ws;
  float* dist = (float*)ws;                        // 16*3136 floats   @ 0
  float* tmp1 = (float*)(ws + 204800);             // 16*224*224 floats
  unsigned int* mm = (unsigned int*)(ws + 3416064);

  k_dist<<<NP, 256, 0, stream>>>(emb, means, icov, dist);
  k_rowblur<<<NB * OW, 256, 0, stream>>>(dist, out, mm);   // out as scratch
  k_colblur<<<NB * OW, 256, 0, stream>>>(out, tmp1, mm);
  k_norm<<<NB * OW * OW / 1024, 256, 0, stream>>>((const float4*)tmp1, mm,
                                                  (float4*)out);
}